// Round 1
// baseline (35.547 us; speedup 1.0000x reference)
//
#include <hip/hip_runtime.h>

#define BB 8
#define NN 2048
#define FF 64

// ---------------- Kernel 1: fold attention vectors through projection -------
// ws[i] = sum_o kernel[i,0,o] * attn_self[o];  wn[i] likewise with attn_neigh.
__global__ void fold_kernel(const float* __restrict__ kmat,
                            const float* __restrict__ aks,
                            const float* __restrict__ akn,
                            float* __restrict__ ws, float* __restrict__ wn) {
    int i = threadIdx.x;  // 0..63
    float s = 0.f, t = 0.f;
    #pragma unroll
    for (int o = 0; o < FF; ++o) {
        float k = kmat[i * FF + o];
        s += k * aks[o];
        t += k * akn[o];
    }
    ws[i] = s;
    wn[i] = t;
}

// ---------------- Kernel 2: per-node scalar scores ---------------------------
// S[g] = dot(encode[g,:], ws);  T[g] = dot(encode[g,:], wn);  g = b*N+n.
__global__ __launch_bounds__(256) void scores_kernel(const float* __restrict__ enc,
                                                     const float* __restrict__ ws,
                                                     const float* __restrict__ wn,
                                                     float* __restrict__ S,
                                                     float* __restrict__ T) {
    int g = blockIdx.x * blockDim.x + threadIdx.x;
    if (g >= BB * NN) return;
    const float4* e4 = (const float4*)(enc + (size_t)g * FF);
    const float4* w4 = (const float4*)ws;
    const float4* v4 = (const float4*)wn;
    float s = 0.f, t = 0.f;
    #pragma unroll
    for (int j = 0; j < FF / 4; ++j) {
        float4 e = e4[j];
        float4 w = w4[j];
        float4 v = v4[j];
        s += e.x * w.x + e.y * w.y + e.z * w.z + e.w * w.w;
        t += e.x * v.x + e.y * v.y + e.z * v.z + e.w * v.w;
    }
    S[g] = s;
    T[g] = t;
}

// ---------------- Kernel 3: one block per output row, fused softmax ----------
__device__ __forceinline__ float waveMax(float v) {
    #pragma unroll
    for (int o = 32; o > 0; o >>= 1) v = fmaxf(v, __shfl_xor(v, o, 64));
    return v;
}
__device__ __forceinline__ float waveSum(float v) {
    #pragma unroll
    for (int o = 32; o > 0; o >>= 1) v += __shfl_xor(v, o, 64);
    return v;
}

__global__ __launch_bounds__(256) void softmax_kernel(const float* __restrict__ S,
                                                      const float* __restrict__ T,
                                                      float* __restrict__ out) {
    const int row = blockIdx.x;          // row = b*N + n
    const int b   = row >> 11;           // N = 2048 = 2^11
    const int tid = threadIdx.x;

    const float s = S[row];
    const float4* t4 = (const float4*)(T + (size_t)b * NN);

    float4 ta = t4[tid];        // m = 4*tid .. 4*tid+3
    float4 tb = t4[tid + 256];  // m = 1024 + 4*tid ..

    auto lk = [](float x) { return x > 0.f ? x : 0.2f * x; };
    float l[8];
    l[0] = lk(s + ta.x); l[1] = lk(s + ta.y); l[2] = lk(s + ta.z); l[3] = lk(s + ta.w);
    l[4] = lk(s + tb.x); l[5] = lk(s + tb.y); l[6] = lk(s + tb.z); l[7] = lk(s + tb.w);

    // --- block max ---
    float m8 = l[0];
    #pragma unroll
    for (int k = 1; k < 8; ++k) m8 = fmaxf(m8, l[k]);
    m8 = waveMax(m8);
    __shared__ float redm[4];
    __shared__ float reds[4];
    const int wave = tid >> 6, lane = tid & 63;
    if (lane == 0) redm[wave] = m8;
    __syncthreads();
    const float rowmax = fmaxf(fmaxf(redm[0], redm[1]), fmaxf(redm[2], redm[3]));

    // --- exp + block sum ---
    float e[8];
    float ls = 0.f;
    #pragma unroll
    for (int k = 0; k < 8; ++k) {
        e[k] = __expf(l[k] - rowmax);
        ls += e[k];
    }
    ls = waveSum(ls);
    if (lane == 0) reds[wave] = ls;
    __syncthreads();
    const float inv = 1.f / (reds[0] + reds[1] + reds[2] + reds[3]);

    // --- normalized write (coalesced float4) ---
    float4* o4 = (float4*)(out + (size_t)row * NN);
    float4 oa, ob;
    oa.x = e[0] * inv; oa.y = e[1] * inv; oa.z = e[2] * inv; oa.w = e[3] * inv;
    ob.x = e[4] * inv; ob.y = e[5] * inv; ob.z = e[6] * inv; ob.w = e[7] * inv;
    o4[tid]       = oa;
    o4[tid + 256] = ob;
}

extern "C" void kernel_launch(void* const* d_in, const int* in_sizes, int n_in,
                              void* d_out, int out_size, void* d_ws, size_t ws_size,
                              hipStream_t stream) {
    const float* enc  = (const float*)d_in[0];  // [B,N,F]
    const float* kmat = (const float*)d_in[1];  // [F,1,F]
    const float* aks  = (const float*)d_in[2];  // [F,1,1]
    const float* akn  = (const float*)d_in[3];  // [F,1,1]
    float* out = (float*)d_out;                 // [B,N,N]

    float* W  = (float*)d_ws;
    float* ws = W;              // 64
    float* wn = W + 64;         // 64
    float* S  = W + 128;        // B*N = 16384
    float* T  = W + 128 + BB * NN;  // 16384

    fold_kernel<<<1, 64, 0, stream>>>(kmat, aks, akn, ws, wn);
    scores_kernel<<<(BB * NN + 255) / 256, 256, 0, stream>>>(enc, ws, wn, S, T);
    softmax_kernel<<<BB * NN, 256, 0, stream>>>(S, T, out);
}

// Round 3
// 33.317 us; speedup vs baseline: 1.0669x; 1.0669x over previous
//
#include <hip/hip_runtime.h>

#define BB 8
#define NN 2048
#define FF 64

typedef float f32x4 __attribute__((ext_vector_type(4)));

// ---------------- Kernel A: fused fold + per-node scores ---------------------
// fold: ws[i] = sum_o kernel[i,0,o]*aks[o]; wn[i] likewise (recomputed per block,
// 16 KB L2-hit read, trivial). Then S[g]=dot(enc[g],ws), T[g]=dot(enc[g],wn).
__global__ __launch_bounds__(256) void scores_fused(const float* __restrict__ enc,
                                                    const float* __restrict__ kmat,
                                                    const float* __restrict__ aks,
                                                    const float* __restrict__ akn,
                                                    float* __restrict__ S,
                                                    float* __restrict__ T) {
    __shared__ float ws[FF], wn[FF];
    const int tid = threadIdx.x;
    if (tid < FF) {
        float s = 0.f, t = 0.f;
        #pragma unroll
        for (int o = 0; o < FF; ++o) {
            float k = kmat[tid * FF + o];
            s += k * aks[o];
            t += k * akn[o];
        }
        ws[tid] = s;
        wn[tid] = t;
    }
    __syncthreads();

    const int g = blockIdx.x * 256 + tid;
    const f32x4* e4 = (const f32x4*)(enc + (size_t)g * FF);
    const f32x4* w4 = (const f32x4*)ws;
    const f32x4* v4 = (const f32x4*)wn;
    float s = 0.f, t = 0.f;
    #pragma unroll
    for (int j = 0; j < FF / 4; ++j) {
        f32x4 e = e4[j];
        f32x4 w = w4[j];   // LDS broadcast (same addr all lanes) — conflict-free
        f32x4 v = v4[j];
        s += e.x * w.x + e.y * w.y + e.z * w.z + e.w * w.w;
        t += e.x * v.x + e.y * v.y + e.z * v.z + e.w * v.w;
    }
    S[g] = s;
    T[g] = t;
}

// ---------------- Kernel B: one WAVE per output row, no barriers, no LDS -----
__device__ __forceinline__ float waveMax(float v) {
    #pragma unroll
    for (int o = 32; o > 0; o >>= 1) v = fmaxf(v, __shfl_xor(v, o, 64));
    return v;
}
__device__ __forceinline__ float waveSum(float v) {
    #pragma unroll
    for (int o = 32; o > 0; o >>= 1) v += __shfl_xor(v, o, 64);
    return v;
}

__global__ __launch_bounds__(256) void softmax_kernel(const float* __restrict__ S,
                                                      const float* __restrict__ T,
                                                      float* __restrict__ out) {
    const int wave = threadIdx.x >> 6;
    const int lane = threadIdx.x & 63;
    const int row  = blockIdx.x * 4 + wave;   // row = b*N + n
    const int b    = row >> 11;               // N = 2048 = 2^11

    const float s = S[row];
    const f32x4* t4 = (const f32x4*)(T + (size_t)b * NN);

    auto lk = [](float x) { return x > 0.f ? x : 0.2f * x; };

    // load T row: lane j reads t4[lane + 64*j] -> 1 KB per instruction, coalesced
    f32x4 l[8];
    float m = -3.4e38f;
    #pragma unroll
    for (int j = 0; j < 8; ++j) {
        f32x4 t = t4[lane + 64 * j];
        l[j].x = lk(s + t.x); l[j].y = lk(s + t.y);
        l[j].z = lk(s + t.z); l[j].w = lk(s + t.w);
        m = fmaxf(m, fmaxf(fmaxf(l[j].x, l[j].y), fmaxf(l[j].z, l[j].w)));
    }
    m = waveMax(m);

    float ls = 0.f;
    #pragma unroll
    for (int j = 0; j < 8; ++j) {
        l[j].x = __expf(l[j].x - m); l[j].y = __expf(l[j].y - m);
        l[j].z = __expf(l[j].z - m); l[j].w = __expf(l[j].w - m);
        ls += (l[j].x + l[j].y) + (l[j].z + l[j].w);
    }
    ls = waveSum(ls);
    const float inv = 1.f / ls;

    f32x4* o4 = (f32x4*)(out + (size_t)row * NN);
    #pragma unroll
    for (int j = 0; j < 8; ++j) {
        f32x4 o;
        o.x = l[j].x * inv; o.y = l[j].y * inv;
        o.z = l[j].z * inv; o.w = l[j].w * inv;
        __builtin_nontemporal_store(o, &o4[lane + 64 * j]);
    }
}

extern "C" void kernel_launch(void* const* d_in, const int* in_sizes, int n_in,
                              void* d_out, int out_size, void* d_ws, size_t ws_size,
                              hipStream_t stream) {
    const float* enc  = (const float*)d_in[0];  // [B,N,F]
    const float* kmat = (const float*)d_in[1];  // [F,1,F]
    const float* aks  = (const float*)d_in[2];  // [F,1,1]
    const float* akn  = (const float*)d_in[3];  // [F,1,1]
    float* out = (float*)d_out;                 // [B,N,N]

    float* W = (float*)d_ws;
    float* S = W;                 // B*N = 16384
    float* T = W + BB * NN;       // 16384

    scores_fused<<<BB * NN / 256, 256, 0, stream>>>(enc, kmat, aks, akn, S, T);
    softmax_kernel<<<BB * NN / 4, 256, 0, stream>>>(S, T, out);
}